// Round 1
// baseline (52.383 us; speedup 1.0000x reference)
//
#include <hip/hip_runtime.h>

#define HH 512
#define WW 512
#define CH 3
#define BX 64
#define BY 4
#define TX (BX + 6)   // 70
#define TY (BY + 6)   // 10
#define NELEM (CH * TY * TX)  // 2100

__global__ __launch_bounds__(BX * BY)
void bilateral_kernel(const float* __restrict__ in, float* __restrict__ out) {
    __shared__ float sm[CH][TY][TX];

    const int bx0 = blockIdx.x * BX;
    const int by0 = blockIdx.y * BY;
    const int b   = blockIdx.z;
    const int tid = threadIdx.y * BX + threadIdx.x;

    const float* inb = in + (size_t)b * CH * HH * WW;

    // cooperative halo load with reflect indexing (jnp 'reflect': mirror, edge not repeated)
    float* smf = &sm[0][0][0];
    for (int idx = tid; idx < NELEM; idx += BX * BY) {
        int c  = idx / (TY * TX);
        int r  = idx - c * (TY * TX);
        int ty = r / TX;
        int tx = r - ty * TX;
        int gy = by0 + ty - 3;
        int gx = bx0 + tx - 3;
        gy = (gy < 0) ? -gy : ((gy >= HH) ? 2 * (HH - 1) - gy : gy);
        gx = (gx < 0) ? -gx : ((gx >= WW) ? 2 * (WW - 1) - gx : gx);
        smf[idx] = inb[(c * HH + gy) * WW + gx];
    }
    __syncthreads();

    const int lx = threadIdx.x;
    const int ly = threadIdx.y;

    const float c0 = sm[0][ly + 3][lx + 3];
    const float c1 = sm[1][ly + 3][lx + 3];
    const float c2 = sm[2][ly + 3][lx + 3];

    float n0 = 0.f, n1 = 0.f, n2 = 0.f, den = 0.f;

#pragma unroll
    for (int i = 0; i < 7; ++i) {
#pragma unroll
        for (int j = 0; j < 7; ++j) {
            const float p0 = sm[0][ly + i][lx + j];
            const float p1 = sm[1][ly + i][lx + j];
            const float p2 = sm[2][ly + i][lx + j];
            const float d  = fabsf(p0 - c0) + fabsf(p1 - c1) + fabsf(p2 - c2);
            // spatial log-weight: -((i-3)^2 + (j-3)^2) / (2 * 1.5^2); normalization cancels in num/den
            const float lnw = -(float)((i - 3) * (i - 3) + (j - 3) * (j - 3)) * (1.0f / 4.5f);
            const float w = __expf(fmaf(d * d, -50.0f, lnw));
            n0 = fmaf(w, p0, n0);
            n1 = fmaf(w, p1, n1);
            n2 = fmaf(w, p2, n2);
            den += w;
        }
    }

    const float inv = 1.0f / den;  // den >= 1 (center tap weight == 1)
    const int y = by0 + ly;
    const int x = bx0 + lx;
    float* outb = out + (size_t)b * CH * HH * WW;
    outb[(0 * HH + y) * WW + x] = n0 * inv;
    outb[(1 * HH + y) * WW + x] = n1 * inv;
    outb[(2 * HH + y) * WW + x] = n2 * inv;
}

extern "C" void kernel_launch(void* const* d_in, const int* in_sizes, int n_in,
                              void* d_out, int out_size, void* d_ws, size_t ws_size,
                              hipStream_t stream) {
    const float* in = (const float*)d_in[0];
    float* out = (float*)d_out;
    const int B = in_sizes[0] / (CH * HH * WW);
    dim3 grid(WW / BX, HH / BY, B);
    dim3 block(BX, BY, 1);
    bilateral_kernel<<<grid, block, 0, stream>>>(in, out);
}